// Round 8
// baseline (68.669 us; speedup 1.0000x reference)
//
#include <hip/hip_runtime.h>

// Deformable 3x3 local correlation. Channel-packed LDS (4ch per 16B cell),
// b128 gathers, reg-staged transpose, T14 prefetch. 1 block/CU.
// LDS deliberately >80KB: forces compiler to 1 WG/CU occupancy target ->
// 128-VGPR budget -> no spill (r6/r7 lesson: 76KB LDS -> 2 WG target -> 64
// VGPR cap -> 40 regs spilled -> 190MB scratch traffic).
// left/right (2,128,64,256) f32, extra_offset (2,18,64,256) f32,
// out (2,72,64,256) f32. GROUPS=8, cg=16, S=9.

#define NB 2
#define CC 128
#define HH 64
#define WW 256
#define GG 8
#define CG 16
#define SS 9
#define HW (HH * WW)
#define TY 4                    // output rows per block
#define RW 7                    // staged rows h0-RW .. h0+TY+RW-1
#define NSLOT 21                // 1 top guard + 18 data + 2 bottom guard
#define CROW 1056               // dwords per row slot: 4 guard + 4*257 data + pad (mult of 32)
#define SMEMDW (NSLOT * CROW)   // 22176 dw = 88.7 KB  (>81920B -> 1 WG/CU)

// ---- stage chunk (4 channels) : global -> regs ----
#define LOADR(VV, LV, CH0)                                                     \
  _Pragma("unroll")                                                            \
  for (int rep = 0; rep < 2; ++rep) {                                          \
    const int r = wv + rep * 16;                                               \
    if (r < nrows) {                                                           \
      const float* src = rnb + (size_t)(gch + (CH0)) * HW + (row0 + r) * WW + lane; \
      _Pragma("unroll")                                                        \
      for (int c2 = 0; c2 < 4; ++c2)                                           \
        _Pragma("unroll")                                                      \
        for (int i = 0; i < 4; ++i)                                            \
          VV[rep][i * 4 + c2] = src[c2 * HW + 64 * i];                         \
    }                                                                          \
  }                                                                            \
  _Pragma("unroll")                                                            \
  for (int c2 = 0; c2 < 4; ++c2) LV[c2] = lp[(size_t)((CH0) + c2) * HW];

// ---- regs -> LDS (thread-local 4x4 transpose, natural b128 write pattern) ----
#define WRITER(VV)                                                             \
  _Pragma("unroll")                                                            \
  for (int rep = 0; rep < 2; ++rep) {                                          \
    const int r = wv + rep * 16;                                               \
    if (r < nrows) {                                                           \
      float4* dst = (float4*)&smem[(sbase + r) * CROW + 4 * (lane + 1)];       \
      _Pragma("unroll")                                                        \
      for (int i = 0; i < 4; ++i)                                              \
        dst[64 * i] = make_float4(VV[rep][i * 4 + 0], VV[rep][i * 4 + 1],      \
                                  VV[rep][i * 4 + 2], VV[rep][i * 4 + 3]);     \
    }                                                                          \
  }

// ---- compute one 4-channel chunk ----
#define COMPUTE(LV, CH0)                                                       \
  if (__builtin_expect(badmask == 0, 1)) {                                     \
    _Pragma("unroll")                                                          \
    for (int s = 0; s < SS; ++s) {                                             \
      const char* p = sb + lbase[s];                                           \
      const float4 A = *(const float4*)(p);                                    \
      const float4 B = *(const float4*)(p + 16);                               \
      const float4 C = *(const float4*)(p + CROW * 4);                         \
      const float4 D = *(const float4*)(p + CROW * 4 + 16);                    \
      acc[s] += LV[0] * (wA[s] * A.x + wB[s] * B.x + wC[s] * C.x + wD[s] * D.x) \
              + LV[1] * (wA[s] * A.y + wB[s] * B.y + wC[s] * C.y + wD[s] * D.y) \
              + LV[2] * (wA[s] * A.z + wB[s] * B.z + wC[s] * C.z + wD[s] * D.z) \
              + LV[3] * (wA[s] * A.w + wB[s] * B.w + wC[s] * C.w + wD[s] * D.w); \
    }                                                                          \
  } else {                                                                     \
    const float* rq = rnb + (size_t)(gch + (CH0)) * HW;                        \
    _Pragma("unroll")                                                          \
    for (int s = 0; s < SS; ++s) {                                             \
      const float x = (float)(s / 3 - 1) + eob[(2 * s) * HW] + (float)wcol;    \
      const float y = (float)(s % 3 - 1) + eob[(2 * s + 1) * HW] + (float)h;   \
      const float x0f = floorf(x), y0f = floorf(y);                            \
      const float fx0 = x - x0f, fx1 = 1.0f - fx0;                             \
      const float fy0 = y - y0f, fy1 = 1.0f - fy0;                             \
      const int x0 = (int)x0f, y0 = (int)y0f;                                  \
      const int x1 = x0 + 1,   y1 = y0 + 1;                                    \
      const bool vx0 = (unsigned)x0 < (unsigned)WW;                            \
      const bool vx1 = (unsigned)x1 < (unsigned)WW;                            \
      const bool vy0 = (unsigned)y0 < (unsigned)HH;                            \
      const bool vy1 = (unsigned)y1 < (unsigned)HH;                            \
      const float a = (vx0 && vy0) ? fx1 * fy1 : 0.0f;                         \
      const float b = (vx1 && vy0) ? fx0 * fy1 : 0.0f;                         \
      const float c3 = (vx0 && vy1) ? fx1 * fy0 : 0.0f;                        \
      const float d = (vx1 && vy1) ? fx0 * fy0 : 0.0f;                         \
      const int cx0 = min(max(x0, 0), WW - 1), cx1 = min(max(x1, 0), WW - 1);  \
      const int cy0 = min(max(y0, 0), HH - 1), cy1 = min(max(y1, 0), HH - 1);  \
      _Pragma("unroll")                                                        \
      for (int c2 = 0; c2 < 4; ++c2) {                                         \
        const float* rp2 = rq + (size_t)c2 * HW;                               \
        const float v = a * rp2[cy0 * WW + cx0] + b * rp2[cy0 * WW + cx1]      \
                      + c3 * rp2[cy1 * WW + cx0] + d * rp2[cy1 * WW + cx1];    \
        acc[s] += LV[c2] * v;                                                  \
      }                                                                        \
    }                                                                          \
  }

__global__ __launch_bounds__(1024, 4) void corr_kernel(
    const float* __restrict__ left, const float* __restrict__ right,
    const float* __restrict__ eo, float* __restrict__ out)
{
    __shared__ float smem[SMEMDW];

    const int tid = threadIdx.x;
    const int lane = tid & 63;
    const int wv = tid >> 6;                 // wave 0..15
    const int bid = blockIdx.x;
    const int g = bid & (GG - 1);
    const int h0 = ((bid >> 3) & 15) << 2;
    const int n = bid >> 7;
    const int gch = g * CG;                  // first channel of this group

    const int virt_row0 = h0 - RW;           // slot 1 maps here
    const int row0 = max(0, virt_row0);
    const int row_last = min(HH - 1, h0 + TY + RW - 1);  // h0+10 in the interior
    const int nrows = row_last - row0 + 1;               // <= 18
    const int sbase = row0 - virt_row0 + 1;

    const int hh = tid >> 8;                 // 0..3 (wave-uniform)
    const int h = h0 + hh;
    const int wcol = tid & 255;
    const int pix = h * WW + wcol;

    const float* rnb = right + (size_t)n * CC * HW;
    const float* lp  = left  + (size_t)(n * CC + gch) * HW + pix;
    const float* eob = eo + (size_t)n * SS * 2 * HW + pix;
    const char* sb = (const char*)smem;

    int lbase[SS];
    float wA[SS], wB[SS], wC[SS], wD[SS];
    int badmask = 0;

#pragma unroll
    for (int s = 0; s < SS; ++s) {
        const float x = (float)(s / 3 - 1) + eob[(2 * s) * HW] + (float)wcol;
        const float y = (float)(s % 3 - 1) + eob[(2 * s + 1) * HW] + (float)h;
        const float x0f = floorf(x), y0f = floorf(y);
        const float fx0 = x - x0f, fx1 = 1.0f - fx0;
        const float fy0 = y - y0f, fy1 = 1.0f - fy0;
        const int x0 = (int)x0f, y0 = (int)y0f;
        const int x1 = x0 + 1,   y1 = y0 + 1;
        const bool vx0 = (unsigned)x0 < (unsigned)WW;
        const bool vx1 = (unsigned)x1 < (unsigned)WW;
        const bool vy0 = (unsigned)y0 < (unsigned)HH;
        const bool vy1 = (unsigned)y1 < (unsigned)HH;

        wA[s] = (vx0 && vy0) ? fx1 * fy1 : 0.0f;   // (x0,y0) -> +0
        wB[s] = (vx1 && vy0) ? fx0 * fy1 : 0.0f;   // (x1,y0) -> +16B
        wC[s] = (vx0 && vy1) ? fx1 * fy0 : 0.0f;   // (x0,y1) -> +CROW*4
        wD[s] = (vx1 && vy1) ? fx0 * fy0 : 0.0f;   // (x1,y1) -> +CROW*4+16

        const int xc = min(max(x0, -1), WW);                       // [-1,256]
        const int rr = min(max(y0 - virt_row0 + 1, 0), NSLOT - 2); // [0,19]
        lbase[s] = rr * (CROW * 4) + 16 * (xc + 1);

        if ((vy0 && (y0 < row0 || y0 > row_last)) ||
            (vy1 && (y1 < row0 || y1 > row_last)))
            badmask |= 1 << s;
    }

    float acc[SS];
#pragma unroll
    for (int s = 0; s < SS; ++s) acc[s] = 0.0f;

    float vvA[2][16], vvB[2][16], lvA[4], lvB[4];

    // prologue: issue chunk-0 loads, zero the buffer (guards must read 0)
    LOADR(vvA, lvA, 0)
    for (int i = tid; i < SMEMDW / 4; i += 1024)
        *(float4*)&smem[4 * i] = make_float4(0.f, 0.f, 0.f, 0.f);
    __syncthreads();                  // zero visible
    WRITER(vvA)
    __syncthreads();                  // chunk 0 staged

    LOADR(vvB, lvB, 4)                // prefetch chunk 1
    COMPUTE(lvA, 0)
    __syncthreads();                  // all waves done reading buffer
    WRITER(vvB)
    __syncthreads();

    LOADR(vvA, lvA, 8)                // prefetch chunk 2
    COMPUTE(lvB, 4)
    __syncthreads();
    WRITER(vvA)
    __syncthreads();

    LOADR(vvB, lvB, 12)               // prefetch chunk 3
    COMPUTE(lvA, 8)
    __syncthreads();
    WRITER(vvB)
    __syncthreads();

    COMPUTE(lvB, 12)

    float* ob = out + ((size_t)(n * GG + g) * SS) * HW + pix;
#pragma unroll
    for (int s = 0; s < SS; ++s)
        ob[s * HW] = acc[s] * (1.0f / CG);
}

extern "C" void kernel_launch(void* const* d_in, const int* in_sizes, int n_in,
                              void* d_out, int out_size, void* d_ws, size_t ws_size,
                              hipStream_t stream) {
    const float* left  = (const float*)d_in[0];
    const float* right = (const float*)d_in[1];
    const float* eo    = (const float*)d_in[2];
    float* out = (float*)d_out;
    (void)d_ws; (void)ws_size; (void)in_sizes; (void)n_in; (void)out_size;

    dim3 grid(NB * (HH / TY) * GG);   // 256 blocks: (n, h-tile, group)
    dim3 block(1024);                  // 16 waves; thread = (hh, w)
    corr_kernel<<<grid, block, 0, stream>>>(left, right, eo, out);
}

// Round 9
// 48.569 us; speedup vs baseline: 1.4138x; 1.4138x over previous
//
#include <hip/hip_runtime.h>

// Deformable 3x3 local correlation. Channel-packed LDS (4ch per 16B cell),
// b128 gathers, reg-staged transpose, T14 prefetch. 1 block/CU.
// Register budget pinned via amdgpu_waves_per_eu(4,4): 512-reg pool / 4
// waves per SIMD = 128 VGPRs -> no spill. (r6-r8 lesson: default heuristic
// targets 8 waves/EU -> 64-VGPR cap -> ~40 spilled regs -> 130-190MB of
// scratch traffic; __launch_bounds__(1024,4) and LDS>80KB both failed to
// change it. WRITE_SIZE >> 9.2MB output is the spill tripwire.)
// left/right (2,128,64,256) f32, extra_offset (2,18,64,256) f32,
// out (2,72,64,256) f32. GROUPS=8, cg=16, S=9.

#define NB 2
#define CC 128
#define HH 64
#define WW 256
#define GG 8
#define CG 16
#define SS 9
#define HW (HH * WW)
#define TY 4                    // output rows per block
#define RW 5                    // staged rows h0-RW .. h0+TY+RW-1 (15 rows interior)
#define NSLOT 18                // 1 top guard + 15 data + 2 bottom guard
#define CROW 1056               // dwords per row slot: 4 guard + 4*257 data + pad (mult of 32)
#define SMEMDW (NSLOT * CROW)   // 19008 dw = 76 KB

// ---- stage chunk (4 channels) : global -> regs (nrows <= 15 < 16 waves) ----
#define LOADR(VV, LV, CH0)                                                     \
  if (wv < nrows) {                                                            \
    const float* src = rnb + (size_t)(gch + (CH0)) * HW + (row0 + wv) * WW + lane; \
    _Pragma("unroll")                                                          \
    for (int c2 = 0; c2 < 4; ++c2)                                             \
      _Pragma("unroll")                                                        \
      for (int i = 0; i < 4; ++i)                                              \
        VV[i * 4 + c2] = src[c2 * HW + 64 * i];                                \
  }                                                                            \
  _Pragma("unroll")                                                            \
  for (int c2 = 0; c2 < 4; ++c2) LV[c2] = lp[(size_t)((CH0) + c2) * HW];

// ---- regs -> LDS (thread-local 4x4 transpose, natural b128 write pattern) ----
#define WRITER(VV)                                                             \
  if (wv < nrows) {                                                            \
    float4* dst = (float4*)&smem[(sbase + wv) * CROW + 4 * (lane + 1)];        \
    _Pragma("unroll")                                                          \
    for (int i = 0; i < 4; ++i)                                                \
      dst[64 * i] = make_float4(VV[i * 4 + 0], VV[i * 4 + 1],                  \
                                VV[i * 4 + 2], VV[i * 4 + 3]);                 \
  }

// ---- compute one 4-channel chunk ----
#define COMPUTE(LV, CH0)                                                       \
  if (__builtin_expect(badmask == 0, 1)) {                                     \
    _Pragma("unroll")                                                          \
    for (int s = 0; s < SS; ++s) {                                             \
      const char* p = sb + lbase[s];                                           \
      const float4 A = *(const float4*)(p);                                    \
      const float4 B = *(const float4*)(p + 16);                               \
      const float4 C = *(const float4*)(p + CROW * 4);                         \
      const float4 D = *(const float4*)(p + CROW * 4 + 16);                    \
      acc[s] += LV[0] * (wA[s] * A.x + wB[s] * B.x + wC[s] * C.x + wD[s] * D.x) \
              + LV[1] * (wA[s] * A.y + wB[s] * B.y + wC[s] * C.y + wD[s] * D.y) \
              + LV[2] * (wA[s] * A.z + wB[s] * B.z + wC[s] * C.z + wD[s] * D.z) \
              + LV[3] * (wA[s] * A.w + wB[s] * B.w + wC[s] * C.w + wD[s] * D.w); \
    }                                                                          \
  } else {                                                                     \
    const float* rq = rnb + (size_t)(gch + (CH0)) * HW;                        \
    _Pragma("unroll")                                                          \
    for (int s = 0; s < SS; ++s) {                                             \
      const float x = (float)(s / 3 - 1) + eob[(2 * s) * HW] + (float)wcol;    \
      const float y = (float)(s % 3 - 1) + eob[(2 * s + 1) * HW] + (float)h;   \
      const float x0f = floorf(x), y0f = floorf(y);                            \
      const float fx0 = x - x0f, fx1 = 1.0f - fx0;                             \
      const float fy0 = y - y0f, fy1 = 1.0f - fy0;                             \
      const int x0 = (int)x0f, y0 = (int)y0f;                                  \
      const int x1 = x0 + 1,   y1 = y0 + 1;                                    \
      const bool vx0 = (unsigned)x0 < (unsigned)WW;                            \
      const bool vx1 = (unsigned)x1 < (unsigned)WW;                            \
      const bool vy0 = (unsigned)y0 < (unsigned)HH;                            \
      const bool vy1 = (unsigned)y1 < (unsigned)HH;                            \
      const float a = (vx0 && vy0) ? fx1 * fy1 : 0.0f;                         \
      const float b = (vx1 && vy0) ? fx0 * fy1 : 0.0f;                         \
      const float c3 = (vx0 && vy1) ? fx1 * fy0 : 0.0f;                        \
      const float d = (vx1 && vy1) ? fx0 * fy0 : 0.0f;                         \
      const int cx0 = min(max(x0, 0), WW - 1), cx1 = min(max(x1, 0), WW - 1);  \
      const int cy0 = min(max(y0, 0), HH - 1), cy1 = min(max(y1, 0), HH - 1);  \
      _Pragma("unroll")                                                        \
      for (int c2 = 0; c2 < 4; ++c2) {                                         \
        const float* rp2 = rq + (size_t)c2 * HW;                               \
        const float v = a * rp2[cy0 * WW + cx0] + b * rp2[cy0 * WW + cx1]      \
                      + c3 * rp2[cy1 * WW + cx0] + d * rp2[cy1 * WW + cx1];    \
        acc[s] += LV[c2] * v;                                                  \
      }                                                                        \
    }                                                                          \
  }

__global__ __attribute__((amdgpu_flat_work_group_size(1024, 1024),
                          amdgpu_waves_per_eu(4, 4)))
void corr_kernel(
    const float* __restrict__ left, const float* __restrict__ right,
    const float* __restrict__ eo, float* __restrict__ out)
{
    __shared__ float smem[SMEMDW];

    const int tid = threadIdx.x;
    const int lane = tid & 63;
    const int wv = tid >> 6;                 // wave 0..15
    const int bid = blockIdx.x;
    const int g = bid & (GG - 1);
    const int h0 = ((bid >> 3) & 15) << 2;
    const int n = bid >> 7;
    const int gch = g * CG;                  // first channel of this group

    const int virt_row0 = h0 - RW;           // slot 1 maps here
    const int row0 = max(0, virt_row0);
    const int row_last = min(HH - 1, h0 + TY + RW - 1);  // h0+8 in the interior
    const int nrows = row_last - row0 + 1;               // <= 15
    const int sbase = row0 - virt_row0 + 1;

    const int hh = tid >> 8;                 // 0..3 (wave-uniform)
    const int h = h0 + hh;
    const int wcol = tid & 255;
    const int pix = h * WW + wcol;

    const float* rnb = right + (size_t)n * CC * HW;
    const float* lp  = left  + (size_t)(n * CC + gch) * HW + pix;
    const float* eob = eo + (size_t)n * SS * 2 * HW + pix;
    const char* sb = (const char*)smem;

    int lbase[SS];
    float wA[SS], wB[SS], wC[SS], wD[SS];
    int badmask = 0;

#pragma unroll
    for (int s = 0; s < SS; ++s) {
        const float x = (float)(s / 3 - 1) + eob[(2 * s) * HW] + (float)wcol;
        const float y = (float)(s % 3 - 1) + eob[(2 * s + 1) * HW] + (float)h;
        const float x0f = floorf(x), y0f = floorf(y);
        const float fx0 = x - x0f, fx1 = 1.0f - fx0;
        const float fy0 = y - y0f, fy1 = 1.0f - fy0;
        const int x0 = (int)x0f, y0 = (int)y0f;
        const int x1 = x0 + 1,   y1 = y0 + 1;
        const bool vx0 = (unsigned)x0 < (unsigned)WW;
        const bool vx1 = (unsigned)x1 < (unsigned)WW;
        const bool vy0 = (unsigned)y0 < (unsigned)HH;
        const bool vy1 = (unsigned)y1 < (unsigned)HH;

        wA[s] = (vx0 && vy0) ? fx1 * fy1 : 0.0f;   // (x0,y0) -> +0
        wB[s] = (vx1 && vy0) ? fx0 * fy1 : 0.0f;   // (x1,y0) -> +16B
        wC[s] = (vx0 && vy1) ? fx1 * fy0 : 0.0f;   // (x0,y1) -> +CROW*4
        wD[s] = (vx1 && vy1) ? fx0 * fy0 : 0.0f;   // (x1,y1) -> +CROW*4+16

        const int xc = min(max(x0, -1), WW);                       // [-1,256]
        const int rr = min(max(y0 - virt_row0 + 1, 0), NSLOT - 2); // [0,16]
        lbase[s] = rr * (CROW * 4) + 16 * (xc + 1);

        if ((vy0 && (y0 < row0 || y0 > row_last)) ||
            (vy1 && (y1 < row0 || y1 > row_last)))
            badmask |= 1 << s;
    }

    float acc[SS];
#pragma unroll
    for (int s = 0; s < SS; ++s) acc[s] = 0.0f;

    float vvA[16], vvB[16], lvA[4], lvB[4];

    // prologue: issue chunk-0 loads, zero the buffer (guards must read 0)
    LOADR(vvA, lvA, 0)
    for (int i = tid; i < SMEMDW / 4; i += 1024)
        *(float4*)&smem[4 * i] = make_float4(0.f, 0.f, 0.f, 0.f);
    __syncthreads();                  // zero visible
    WRITER(vvA)
    __syncthreads();                  // chunk 0 staged

    LOADR(vvB, lvB, 4)                // prefetch chunk 1
    COMPUTE(lvA, 0)
    __syncthreads();                  // all waves done reading buffer
    WRITER(vvB)
    __syncthreads();

    LOADR(vvA, lvA, 8)                // prefetch chunk 2
    COMPUTE(lvB, 4)
    __syncthreads();
    WRITER(vvA)
    __syncthreads();

    LOADR(vvB, lvB, 12)               // prefetch chunk 3
    COMPUTE(lvA, 8)
    __syncthreads();
    WRITER(vvB)
    __syncthreads();

    COMPUTE(lvB, 12)

    float* ob = out + ((size_t)(n * GG + g) * SS) * HW + pix;
#pragma unroll
    for (int s = 0; s < SS; ++s)
        ob[s * HW] = acc[s] * (1.0f / CG);
}

extern "C" void kernel_launch(void* const* d_in, const int* in_sizes, int n_in,
                              void* d_out, int out_size, void* d_ws, size_t ws_size,
                              hipStream_t stream) {
    const float* left  = (const float*)d_in[0];
    const float* right = (const float*)d_in[1];
    const float* eo    = (const float*)d_in[2];
    float* out = (float*)d_out;
    (void)d_ws; (void)ws_size; (void)in_sizes; (void)n_in; (void)out_size;

    dim3 grid(NB * (HH / TY) * GG);   // 256 blocks: (n, h-tile, group)
    dim3 block(1024);                  // 16 waves; thread = (hh, w)
    corr_kernel<<<grid, block, 0, stream>>>(left, right, eo, out);
}

// Round 10
// 36.993 us; speedup vs baseline: 1.8563x; 1.3129x over previous
//
#include <hip/hip_runtime.h>
#include <stdint.h>

// Deformable 3x3 local correlation. Plane-linear LDS (round-4 structure:
// global_load_lds staging, no reg-staging arrays -> fits 64 VGPRs, no spill),
// plus: ds_read2-pairable taps (adjacent-dword reads off one base) and
// slot stride 288 (mult of 32 dwords -> row-independent banks, 2-way free).
// left/right (2,128,64,256) f32, extra_offset (2,18,64,256) f32,
// out (2,72,64,256) f32. GROUPS=8, cg=16, S=9.

#define NB 2
#define CC 128
#define HH 64
#define WW 256
#define GG 8
#define CG 16
#define SS 9
#define HW (HH * WW)
#define TY 4                     // output rows per block
#define RW 6                     // staged rows h0-RW .. h0+TY+RW-1 (16 interior)
#define NSLOT 18                 // 1 top guard + 16 data + 1 bottom guard
#define SLOTDW 288               // dwords per slot (multiple of 32; 16B-aligned)
#define B0 4                     // data starts at dword 4 (x=-1 -> dword 3)
#define BUFDW (NSLOT * SLOTDW)   // 5184 dw = 20.7 KB per buffer

typedef __attribute__((address_space(3))) uint32_t lds_t;
typedef const __attribute__((address_space(1))) uint32_t glb_t;

// stage one channel plane's window into buffer at BOFS_DW (dwords).
// wave wv stages row wv: 64 lanes x 16B = 1024B = one full row, one inst.
#define STAGE(BOFS_DW, RPCH)                                                   \
  if (wv < nrows) {                                                            \
    const float* src = (RPCH) + (row0 + wv) * WW + (lane << 2);                \
    lds_t* dst = (lds_t*)&smem[(BOFS_DW) + (sbase + wv) * SLOTDW + B0];        \
    __builtin_amdgcn_global_load_lds((glb_t*)src, dst, 16, 0, 0);              \
  }

#define COMPUTE(BOFS, RPC)                                                     \
  if (__builtin_expect(badmask == 0, 1)) {                                     \
    _Pragma("unroll")                                                          \
    for (int s = 0; s < SS; ++s) {                                             \
      const float* p0 = (const float*)(sb + (BOFS) * 4 + lbase[s]);            \
      const float* p1 = p0 + SLOTDW;                                           \
      const float A = p0[0], B = p0[1];     /* ds_read2_b32 pair */            \
      const float C = p1[0], D = p1[1];     /* ds_read2_b32 pair */            \
      acc[s] += lv * (wA[s] * A + wB[s] * B + wC[s] * C + wD[s] * D);          \
    }                                                                          \
  } else {                                                                     \
    _Pragma("unroll")                                                          \
    for (int s = 0; s < SS; ++s) {                                             \
      const float x = (float)(s / 3 - 1) + eob[(2 * s) * HW] + (float)wcol;    \
      const float y = (float)(s % 3 - 1) + eob[(2 * s + 1) * HW] + (float)h;   \
      const float x0f = floorf(x), y0f = floorf(y);                            \
      const float fx0 = x - x0f, fx1 = 1.0f - fx0;                             \
      const float fy0 = y - y0f, fy1 = 1.0f - fy0;                             \
      const int x0 = (int)x0f, y0 = (int)y0f;                                  \
      const int x1 = x0 + 1,   y1 = y0 + 1;                                    \
      const bool vx0 = (unsigned)x0 < (unsigned)WW;                            \
      const bool vx1 = (unsigned)x1 < (unsigned)WW;                            \
      const bool vy0 = (unsigned)y0 < (unsigned)HH;                            \
      const bool vy1 = (unsigned)y1 < (unsigned)HH;                            \
      const float a = (vx0 && vy0) ? fx1 * fy1 : 0.0f;                         \
      const float b = (vx1 && vy0) ? fx0 * fy1 : 0.0f;                         \
      const float c2 = (vx0 && vy1) ? fx1 * fy0 : 0.0f;                        \
      const float d = (vx1 && vy1) ? fx0 * fy0 : 0.0f;                         \
      const int cx0 = min(max(x0, 0), WW - 1), cx1 = min(max(x1, 0), WW - 1);  \
      const int cy0 = min(max(y0, 0), HH - 1), cy1 = min(max(y1, 0), HH - 1);  \
      const float v = a * (RPC)[cy0 * WW + cx0] + b * (RPC)[cy0 * WW + cx1]    \
                    + c2 * (RPC)[cy1 * WW + cx0] + d * (RPC)[cy1 * WW + cx1];  \
      acc[s] += lv * v;                                                        \
    }                                                                          \
  }

__global__ __launch_bounds__(1024) void corr_kernel(
    const float* __restrict__ left, const float* __restrict__ right,
    const float* __restrict__ eo, float* __restrict__ out)
{
    __shared__ float smem[2 * BUFDW];   // 41.5 KB

    const int tid = threadIdx.x;
    const int lane = tid & 63;
    const int wv = tid >> 6;                 // wave 0..15
    const int bid = blockIdx.x;
    const int g = bid & (GG - 1);
    const int h0 = ((bid >> 3) & 15) << 2;
    const int n = bid >> 7;
    const int gch = g * CG;

    const int virt_row0 = h0 - RW;                        // slot 1 maps here
    const int row0 = max(0, virt_row0);
    const int row_last = min(HH - 1, h0 + TY + RW - 1);   // h0+9 interior
    const int nrows = row_last - row0 + 1;                // <= 16
    const int sbase = row0 - virt_row0 + 1;

    const int hh = tid >> 8;                 // 0..3 (wave-uniform)
    const int h = h0 + hh;
    const int wcol = tid & 255;
    const int pix = h * WW + wcol;

    const float* rnb = right + (size_t)n * CC * HW;
    const float* lp  = left  + (size_t)(n * CC + gch) * HW + pix;
    const float* eob = eo + (size_t)n * SS * 2 * HW + pix;
    const char* sb = (const char*)smem;

    int lbase[SS];
    float wA[SS], wB[SS], wC[SS], wD[SS];
    int badmask = 0;

#pragma unroll
    for (int s = 0; s < SS; ++s) {
        const float x = (float)(s / 3 - 1) + eob[(2 * s) * HW] + (float)wcol;
        const float y = (float)(s % 3 - 1) + eob[(2 * s + 1) * HW] + (float)h;
        const float x0f = floorf(x), y0f = floorf(y);
        const float fx0 = x - x0f, fx1 = 1.0f - fx0;
        const float fy0 = y - y0f, fy1 = 1.0f - fy0;
        const int x0 = (int)x0f, y0 = (int)y0f;
        const int x1 = x0 + 1,   y1 = y0 + 1;
        const bool vx0 = (unsigned)x0 < (unsigned)WW;
        const bool vx1 = (unsigned)x1 < (unsigned)WW;
        const bool vy0 = (unsigned)y0 < (unsigned)HH;
        const bool vy1 = (unsigned)y1 < (unsigned)HH;

        wA[s] = (vx0 && vy0) ? fx1 * fy1 : 0.0f;   // (x0,y0) -> p0[0]
        wB[s] = (vx1 && vy0) ? fx0 * fy1 : 0.0f;   // (x1,y0) -> p0[1]
        wC[s] = (vx0 && vy1) ? fx1 * fy0 : 0.0f;   // (x0,y1) -> p1[0]
        wD[s] = (vx1 && vy1) ? fx0 * fy0 : 0.0f;   // (x1,y1) -> p1[1]

        const int xc = min(max(x0, -1), WW);                       // [-1,256]
        const int rr = min(max(y0 - virt_row0 + 1, 0), NSLOT - 2); // [0,16]
        lbase[s] = (rr * SLOTDW + B0 + xc) * 4;

        if ((vy0 && (y0 < row0 || y0 > row_last)) ||
            (vy1 && (y1 < row0 || y1 > row_last)))
            badmask |= 1 << s;
    }

    float acc[SS];
#pragma unroll
    for (int s = 0; s < SS; ++s) acc[s] = 0.0f;

    const float* rp = rnb + (size_t)gch * HW;

    // zero both buffers (guard slots/cols must read 0.0)
    for (int i = tid; i < (2 * BUFDW) / 4; i += 1024)
        *(float4*)&smem[4 * i] = make_float4(0.f, 0.f, 0.f, 0.f);
    __syncthreads();                 // zero visible before DMA writes

    STAGE(0, rp)                     // buf0 <- channel 0
    __syncthreads();                 // vmcnt drained: buf0 ready

    const float* rpc = rp;
    for (int c = 0; c < CG; c += 2, rpc += 2 * HW) {
        STAGE(BUFDW, rpc + HW)       // buf1 <- channel c+1 (async)
        {
            const float lv = lp[(size_t)c * HW];
            COMPUTE(0, rpc)
        }
        __syncthreads();             // buf1 ready; buf0 free
        if (c + 2 < CG) { STAGE(0, rpc + 2 * HW) }   // buf0 <- c+2 (async)
        {
            const float lv = lp[(size_t)(c + 1) * HW];
            COMPUTE(BUFDW, rpc + HW)
        }
        __syncthreads();             // buf0 ready; buf1 free
    }

    float* ob = out + ((size_t)(n * GG + g) * SS) * HW + pix;
#pragma unroll
    for (int s = 0; s < SS; ++s)
        ob[s * HW] = acc[s] * (1.0f / CG);
}

extern "C" void kernel_launch(void* const* d_in, const int* in_sizes, int n_in,
                              void* d_out, int out_size, void* d_ws, size_t ws_size,
                              hipStream_t stream) {
    const float* left  = (const float*)d_in[0];
    const float* right = (const float*)d_in[1];
    const float* eo    = (const float*)d_in[2];
    float* out = (float*)d_out;
    (void)d_ws; (void)ws_size; (void)in_sizes; (void)n_in; (void)out_size;

    dim3 grid(NB * (HH / TY) * GG);   // 256 blocks: (n, h-tile, group)
    dim3 block(1024);                  // 16 waves; thread = (hh, w)
    corr_kernel<<<grid, block, 0, stream>>>(left, right, eo, out);
}